// Round 1
// baseline (3173.371 us; speedup 1.0000x reference)
//
#include <hip/hip_runtime.h>
#include <math.h>

#define HD 64
#define RBF 32
#define QD 8
#define DIN 48
#define D2 128
#define D3 192

__device__ __forceinline__ float silu_f(float x) {
    return x / (1.0f + expf(-x));
}

// ---------------- Kernel A: node pre (normalize, decompose, Wt0/1/2) --------
__global__ __launch_bounds__(64) void node_pre(
    const float* __restrict__ X,
    const float* __restrict__ Wt0, const float* __restrict__ Wt1, const float* __restrict__ Wt2,
    float* __restrict__ Xn, float* __restrict__ It, float* __restrict__ At, float* __restrict__ St)
{
    int n = blockIdx.x;
    int h = threadIdx.x;
    const float* Xb = X + (size_t)n * 9 * HD + h;
    float x[9];
    float nrm = 0.f;
#pragma unroll
    for (int i = 0; i < 9; ++i) { x[i] = Xb[i * HD]; nrm += x[i] * x[i]; }
    float inv = 1.0f / (nrm + 1.0f);
#pragma unroll
    for (int i = 0; i < 9; ++i) x[i] *= inv;
    float* Xnb = Xn + (size_t)n * 9 * HD + h;
#pragma unroll
    for (int i = 0; i < 9; ++i) Xnb[i * HD] = x[i];

    float I0 = (x[0] + x[4] + x[8]) * (1.0f / 3.0f);
    __shared__ float comp[10][HD];
    comp[0][h] = I0;
    comp[1][h] = 0.5f * (x[1] - x[3]);
    comp[2][h] = 0.5f * (x[2] - x[6]);
    comp[3][h] = 0.5f * (x[5] - x[7]);
    comp[4][h] = x[0] - I0;
    comp[5][h] = 0.5f * (x[1] + x[3]);
    comp[6][h] = 0.5f * (x[2] + x[6]);
    comp[7][h] = x[4] - I0;
    comp[8][h] = 0.5f * (x[5] + x[7]);
    comp[9][h] = x[8] - I0;
    __syncthreads();
    float acc[10];
#pragma unroll
    for (int i = 0; i < 10; ++i) acc[i] = 0.f;
    for (int k = 0; k < HD; ++k) {
        float w0 = Wt0[k * HD + h];
        float w1 = Wt1[k * HD + h];
        float w2 = Wt2[k * HD + h];
        acc[0] += comp[0][k] * w0;
        acc[1] += comp[1][k] * w1;
        acc[2] += comp[2][k] * w1;
        acc[3] += comp[3][k] * w1;
#pragma unroll
        for (int j = 0; j < 6; ++j) acc[4 + j] += comp[4 + j][k] * w2;
    }
    It[(size_t)n * HD + h] = acc[0];
#pragma unroll
    for (int j = 0; j < 3; ++j) At[((size_t)n * 3 + j) * HD + h] = acc[1 + j];
#pragma unroll
    for (int j = 0; j < 6; ++j) St[((size_t)n * 6 + j) * HD + h] = acc[4 + j];
}

// ---------------- Kernel B: edge MLP + decomposed scatter --------------------
// 64 threads/block = 1 wave, 64 edges/block. lanes = edges during MLP,
// lanes = channels during scatter (via LDS transpose through `buf`).
__global__ __launch_bounds__(64) void edge_mlp_scatter(
    const float* __restrict__ edge_attr, const float* __restrict__ charges,
    const float* __restrict__ edge_weight, const int* __restrict__ edge_index,
    const float* __restrict__ Ws1, const float* __restrict__ bs1,
    const float* __restrict__ Ws2, const float* __restrict__ bs2,
    const float* __restrict__ Ws3, const float* __restrict__ bs3,
    const float* __restrict__ It, const float* __restrict__ At, const float* __restrict__ St,
    float* __restrict__ msgI, float* __restrict__ msgA, float* __restrict__ msgS,
    int E)
{
    __shared__ __align__(16) float buf[64][132];   // reused: h1 / h2 / w-chunk
    __shared__ int rowS[64], colS[64];

    int lane = threadIdx.x;
    int e = blockIdx.x * 64 + lane;
    bool valid = (e < E);
    int row = 0, col = 0;
    float cv = 0.f;
    if (valid) {
        row = edge_index[e];
        col = edge_index[E + e];
        float wgt = edge_weight[e];
        cv = 0.5f * (cosf(wgt * 0.6283185307179586f) + 1.0f);
        cv = (wgt < 5.0f) ? cv : 0.f;
    }
    rowS[lane] = row;
    colS[lane] = col;

    // ---- load per-edge inputs into registers (static-indexed) ----
    float in[DIN];
    if (valid) {
        const float4* ap = (const float4*)(edge_attr + (size_t)e * RBF);
#pragma unroll
        for (int i = 0; i < 8; ++i) {
            float4 v = ap[i];
            in[4 * i + 0] = v.x; in[4 * i + 1] = v.y; in[4 * i + 2] = v.z; in[4 * i + 3] = v.w;
        }
        const float4* qr = (const float4*)(charges + (size_t)row * QD);
        float4 q0 = qr[0], q1 = qr[1];
        in[32] = q0.x; in[33] = q0.y; in[34] = q0.z; in[35] = q0.w;
        in[36] = q1.x; in[37] = q1.y; in[38] = q1.z; in[39] = q1.w;
        const float4* qc = (const float4*)(charges + (size_t)col * QD);
        float4 q2 = qc[0], q3 = qc[1];
        in[40] = q2.x; in[41] = q2.y; in[42] = q2.z; in[43] = q2.w;
        in[44] = q3.x; in[45] = q3.y; in[46] = q3.z; in[47] = q3.w;
    } else {
#pragma unroll
        for (int i = 0; i < DIN; ++i) in[i] = 0.f;
    }

    // ---- layer 1: 48 -> 64 (weights: wave-uniform scalar loads) ----
    for (int c = 0; c < HD; ++c) {
        float a0 = bs1[c], a1 = 0.f, a2 = 0.f, a3 = 0.f;
#pragma unroll
        for (int k = 0; k < DIN; k += 4) {
            a0 += in[k + 0] * Ws1[(k + 0) * HD + c];
            a1 += in[k + 1] * Ws1[(k + 1) * HD + c];
            a2 += in[k + 2] * Ws1[(k + 2) * HD + c];
            a3 += in[k + 3] * Ws1[(k + 3) * HD + c];
        }
        buf[lane][c] = silu_f((a0 + a1) + (a2 + a3));
    }
    __syncthreads();

    // ---- layer 2: 64 -> 128 ----
    float h1r[HD];
#pragma unroll
    for (int k = 0; k < HD; k += 4) {
        float4 v = *(const float4*)&buf[lane][k];
        h1r[k] = v.x; h1r[k + 1] = v.y; h1r[k + 2] = v.z; h1r[k + 3] = v.w;
    }
    __syncthreads();
    for (int c = 0; c < D2; ++c) {
        float a0 = bs2[c], a1 = 0.f, a2 = 0.f, a3 = 0.f;
#pragma unroll
        for (int k = 0; k < HD; k += 4) {
            a0 += h1r[k + 0] * Ws2[(k + 0) * D2 + c];
            a1 += h1r[k + 1] * Ws2[(k + 1) * D2 + c];
            a2 += h1r[k + 2] * Ws2[(k + 2) * D2 + c];
            a3 += h1r[k + 3] * Ws2[(k + 3) * D2 + c];
        }
        buf[lane][c] = silu_f((a0 + a1) + (a2 + a3));
    }
    __syncthreads();

    // ---- layer 3: 128 -> 192, chunked by component, fused scatter ----
    float h2r[D2];
#pragma unroll
    for (int k = 0; k < D2; k += 4) {
        float4 v = *(const float4*)&buf[lane][k];
        h2r[k] = v.x; h2r[k + 1] = v.y; h2r[k + 2] = v.z; h2r[k + 3] = v.w;
    }
    __syncthreads();

    for (int ct = 0; ct < 3; ++ct) {
        for (int cc = 0; cc < HD; ++cc) {
            int c = ct * HD + cc;
            float a0 = bs3[c], a1 = 0.f, a2 = 0.f, a3 = 0.f;
#pragma unroll
            for (int k = 0; k < D2; k += 4) {
                a0 += h2r[k + 0] * Ws3[(k + 0) * D3 + c];
                a1 += h2r[k + 1] * Ws3[(k + 1) * D3 + c];
                a2 += h2r[k + 2] * Ws3[(k + 2) * D3 + c];
                a3 += h2r[k + 3] * Ws3[(k + 3) * D3 + c];
            }
            buf[lane][cc] = silu_f((a0 + a1) + (a2 + a3)) * cv;
        }
        __syncthreads();
        // scatter: lanes = channels, loop over the block's 64 edges.
        // atomics per wave are 256B-contiguous -> coalesced L2 line ops.
        if (ct == 0) {
            for (int ei = 0; ei < 64; ++ei) {
                float wv = buf[ei][lane];
                int r = rowS[ei], cl = colS[ei];
                atomicAdd(&msgI[(size_t)r * HD + lane], wv * It[(size_t)cl * HD + lane]);
            }
        } else if (ct == 1) {
            for (int ei = 0; ei < 64; ++ei) {
                float wv = buf[ei][lane];
                size_t rb = (size_t)rowS[ei] * 3 * HD + lane;
                size_t cb = (size_t)colS[ei] * 3 * HD + lane;
#pragma unroll
                for (int j = 0; j < 3; ++j)
                    atomicAdd(&msgA[rb + j * HD], wv * At[cb + j * HD]);
            }
        } else {
            for (int ei = 0; ei < 64; ++ei) {
                float wv = buf[ei][lane];
                size_t rb = (size_t)rowS[ei] * 6 * HD + lane;
                size_t cb = (size_t)colS[ei] * 6 * HD + lane;
#pragma unroll
                for (int j = 0; j < 6; ++j)
                    atomicAdd(&msgS[rb + j * HD], wv * St[cb + j * HD]);
            }
        }
        __syncthreads();
    }
}

// ---------------- Kernel D: node post ---------------------------------------
__global__ __launch_bounds__(64) void node_post(
    const float* __restrict__ Xn,
    const float* __restrict__ It, const float* __restrict__ At, const float* __restrict__ St,
    const float* __restrict__ msgI, const float* __restrict__ msgA, const float* __restrict__ msgS,
    const float* __restrict__ Wt3, const float* __restrict__ Wt4, const float* __restrict__ Wt5,
    float* __restrict__ out)
{
    int n = blockIdx.x, h = threadIdx.x;
    size_t nH = (size_t)n * HD;
    float mI = msgI[nH + h];
    float mA[3], mS[6], yA[3], yS[6];
#pragma unroll
    for (int j = 0; j < 3; ++j) mA[j] = msgA[((size_t)n * 3 + j) * HD + h];
#pragma unroll
    for (int j = 0; j < 6; ++j) mS[j] = msgS[((size_t)n * 6 + j) * HD + h];
    float yI = It[nH + h];
#pragma unroll
    for (int j = 0; j < 3; ++j) yA[j] = At[((size_t)n * 3 + j) * HD + h];
#pragma unroll
    for (int j = 0; j < 6; ++j) yS[j] = St[((size_t)n * 6 + j) * HD + h];

    float M[3][3] = {
        { mI + mS[0],    mA[0] + mS[1],  mA[1] + mS[2] },
        { -mA[0] + mS[1], mI + mS[3],    mA[2] + mS[4] },
        { -mA[1] + mS[2], -mA[2] + mS[4], mI + mS[5] } };
    float Y[3][3] = {
        { yI + yS[0],    yA[0] + yS[1],  yA[1] + yS[2] },
        { -yA[0] + yS[1], yI + yS[3],    yA[2] + yS[4] },
        { -yA[1] + yS[2], -yA[2] + yS[4], yI + yS[5] } };

    float Cm[3][3];
    float nrm = 0.f;
#pragma unroll
    for (int a = 0; a < 3; ++a) {
#pragma unroll
        for (int b = 0; b < 3; ++b) {
            float s = 0.f;
#pragma unroll
            for (int c = 0; c < 3; ++c) s += M[a][c] * Y[c][b] + Y[a][c] * M[c][b];
            Cm[a][b] = s;
            nrm += s * s;
        }
    }
    float inv = 1.0f / (nrm + 1.0f);
    float tr3 = (Cm[0][0] + Cm[1][1] + Cm[2][2]) * (1.0f / 3.0f);

    __shared__ float comp[10][HD];
    comp[0][h] = tr3 * inv;
    comp[1][h] = 0.5f * (Cm[0][1] - Cm[1][0]) * inv;
    comp[2][h] = 0.5f * (Cm[0][2] - Cm[2][0]) * inv;
    comp[3][h] = 0.5f * (Cm[1][2] - Cm[2][1]) * inv;
    comp[4][h] = (Cm[0][0] - tr3) * inv;
    comp[5][h] = 0.5f * (Cm[0][1] + Cm[1][0]) * inv;
    comp[6][h] = 0.5f * (Cm[0][2] + Cm[2][0]) * inv;
    comp[7][h] = (Cm[1][1] - tr3) * inv;
    comp[8][h] = 0.5f * (Cm[1][2] + Cm[2][1]) * inv;
    comp[9][h] = (Cm[2][2] - tr3) * inv;
    __syncthreads();

    float acc[10];
#pragma unroll
    for (int i = 0; i < 10; ++i) acc[i] = 0.f;
    for (int k = 0; k < HD; ++k) {
        float w3 = Wt3[k * HD + h];
        float w4 = Wt4[k * HD + h];
        float w5 = Wt5[k * HD + h];
        acc[0] += comp[0][k] * w3;
        acc[1] += comp[1][k] * w4;
        acc[2] += comp[2][k] * w4;
        acc[3] += comp[3][k] * w4;
#pragma unroll
        for (int j = 0; j < 6; ++j) acc[4 + j] += comp[4 + j][k] * w5;
    }
    float D[3][3] = {
        { acc[0] + acc[4],  acc[1] + acc[5],  acc[2] + acc[6] },
        { -acc[1] + acc[5], acc[0] + acc[7],  acc[3] + acc[8] },
        { -acc[2] + acc[6], -acc[3] + acc[8], acc[0] + acc[9] } };

    const float* Xb = Xn + (size_t)n * 9 * HD + h;
    float* ob = out + (size_t)n * 9 * HD + h;
#pragma unroll
    for (int a = 0; a < 3; ++a) {
#pragma unroll
        for (int b = 0; b < 3; ++b) {
            float s = 0.f;
#pragma unroll
            for (int c = 0; c < 3; ++c) s += D[a][c] * D[c][b];
            ob[(a * 3 + b) * HD] = Xb[(a * 3 + b) * HD] + D[a][b] + s;
        }
    }
}

// ---------------- launch ------------------------------------------------------
extern "C" void kernel_launch(void* const* d_in, const int* in_sizes, int n_in,
                              void* d_out, int out_size, void* d_ws, size_t ws_size,
                              hipStream_t stream)
{
    const float* X           = (const float*)d_in[0];
    const float* charges     = (const float*)d_in[1];
    const float* edge_weight = (const float*)d_in[2];
    const float* edge_attr   = (const float*)d_in[3];
    const int*   edge_index  = (const int*)d_in[4];
    const float* Ws1 = (const float*)d_in[5];
    const float* bs1 = (const float*)d_in[6];
    const float* Ws2 = (const float*)d_in[7];
    const float* bs2 = (const float*)d_in[8];
    const float* Ws3 = (const float*)d_in[9];
    const float* bs3 = (const float*)d_in[10];
    const float* Wt0 = (const float*)d_in[11];
    const float* Wt1 = (const float*)d_in[12];
    const float* Wt2 = (const float*)d_in[13];
    const float* Wt3 = (const float*)d_in[14];
    const float* Wt4 = (const float*)d_in[15];
    const float* Wt5 = (const float*)d_in[16];

    int N = in_sizes[0] / (9 * HD);
    int E = in_sizes[2];

    float* ws = (float*)d_ws;
    float* Xn   = ws;                               // N*9*H
    float* It   = Xn + (size_t)N * 9 * HD;          // N*H
    float* At   = It + (size_t)N * HD;              // N*3*H
    float* St   = At + (size_t)N * 3 * HD;          // N*6*H
    float* msgI = St + (size_t)N * 6 * HD;          // N*H
    float* msgA = msgI + (size_t)N * HD;            // N*3*H
    float* msgS = msgA + (size_t)N * 3 * HD;        // N*6*H

    // zero message accumulators (contiguous N*10*H floats starting at msgI)
    hipMemsetAsync(msgI, 0, (size_t)N * 10 * HD * sizeof(float), stream);

    node_pre<<<N, 64, 0, stream>>>(X, Wt0, Wt1, Wt2, Xn, It, At, St);

    int nbB = (E + 63) / 64;
    edge_mlp_scatter<<<nbB, 64, 0, stream>>>(
        edge_attr, charges, edge_weight, edge_index,
        Ws1, bs1, Ws2, bs2, Ws3, bs3,
        It, At, St, msgI, msgA, msgS, E);

    node_post<<<N, 64, 0, stream>>>(
        Xn, It, At, St, msgI, msgA, msgS, Wt3, Wt4, Wt5, (float*)d_out);
}

// Round 2
// 633.400 us; speedup vs baseline: 5.0101x; 5.0101x over previous
//
#include <hip/hip_runtime.h>
#include <math.h>

#define HD 64

__device__ __forceinline__ float silu_f(float x) {
    return x / (1.0f + __expf(-x));
}

// ---------------- node_pre: normalize, decompose, Wt0/1/2 -> Tn[n][10][64] --
__global__ __launch_bounds__(64) void node_pre(
    const float* __restrict__ X,
    const float* __restrict__ Wt0, const float* __restrict__ Wt1, const float* __restrict__ Wt2,
    float* __restrict__ Tn)
{
    int n = blockIdx.x;
    int h = threadIdx.x;
    const float* Xb = X + (size_t)n * 9 * HD + h;
    float x[9];
    float nrm = 0.f;
#pragma unroll
    for (int i = 0; i < 9; ++i) { x[i] = Xb[i * HD]; nrm += x[i] * x[i]; }
    float inv = 1.0f / (nrm + 1.0f);
#pragma unroll
    for (int i = 0; i < 9; ++i) x[i] *= inv;

    float I0 = (x[0] + x[4] + x[8]) * (1.0f / 3.0f);
    __shared__ float comp[10][HD];
    comp[0][h] = I0;
    comp[1][h] = 0.5f * (x[1] - x[3]);
    comp[2][h] = 0.5f * (x[2] - x[6]);
    comp[3][h] = 0.5f * (x[5] - x[7]);
    comp[4][h] = x[0] - I0;
    comp[5][h] = 0.5f * (x[1] + x[3]);
    comp[6][h] = 0.5f * (x[2] + x[6]);
    comp[7][h] = x[4] - I0;
    comp[8][h] = 0.5f * (x[5] + x[7]);
    comp[9][h] = x[8] - I0;
    __syncthreads();
    float acc[10];
#pragma unroll
    for (int i = 0; i < 10; ++i) acc[i] = 0.f;
    for (int k = 0; k < HD; ++k) {
        float w0 = Wt0[k * HD + h];
        float w1 = Wt1[k * HD + h];
        float w2 = Wt2[k * HD + h];
        acc[0] += comp[0][k] * w0;
        acc[1] += comp[1][k] * w1;
        acc[2] += comp[2][k] * w1;
        acc[3] += comp[3][k] * w1;
#pragma unroll
        for (int j = 0; j < 6; ++j) acc[4 + j] += comp[4 + j][k] * w2;
    }
    float* tp = Tn + (size_t)n * 640 + h;
#pragma unroll
    for (int i = 0; i < 10; ++i) tp[i * 64] = acc[i];
}

// ---------------- CSR build --------------------------------------------------
__global__ __launch_bounds__(256) void count_kernel(
    const int* __restrict__ edge_index, int* __restrict__ cnt, int E)
{
    int e = blockIdx.x * 256 + threadIdx.x;
    if (e < E) atomicAdd(&cnt[edge_index[e]], 1);
}

__global__ __launch_bounds__(1024) void scan_kernel(
    const int* __restrict__ cnt, int* __restrict__ offs, int* __restrict__ curs, int N)
{
    __shared__ int lds[1024];
    __shared__ int base_s;
    int tid = threadIdx.x;
    if (tid == 0) base_s = 0;
    __syncthreads();
    for (int start = 0; start < N; start += 1024) {
        int i = start + tid;
        int v = (i < N) ? cnt[i] : 0;
        lds[tid] = v;
        __syncthreads();
        for (int off = 1; off < 1024; off <<= 1) {
            int t = (tid >= off) ? lds[tid - off] : 0;
            __syncthreads();
            lds[tid] += t;
            __syncthreads();
        }
        int base = base_s;
        int excl = base + lds[tid] - v;
        if (i < N) { offs[i] = excl; curs[i] = excl; }
        __syncthreads();
        if (tid == 1023) base_s = base + lds[1023];
        __syncthreads();
    }
    if (tid == 0) offs[N] = base_s;
}

__global__ __launch_bounds__(256) void place_kernel(
    const int* __restrict__ edge_index, int* __restrict__ curs, int* __restrict__ order, int E)
{
    int e = blockIdx.x * 256 + threadIdx.x;
    if (e < E) {
        int p = atomicAdd(&curs[edge_index[e]], 1);
        order[p] = e;
    }
}

// ---------------- MLP layer 1: lanes = edges, 48->64 ------------------------
__global__ __launch_bounds__(256) void mlp_l1(
    const float* __restrict__ edge_attr, const float* __restrict__ charges,
    const float* __restrict__ edge_weight, const int* __restrict__ edge_index,
    const float* __restrict__ Ws1, const float* __restrict__ bs1,
    float* __restrict__ h1g, float* __restrict__ cvA, int E)
{
    int e = blockIdx.x * 256 + threadIdx.x;
    bool valid = (e < E);
    int ee = valid ? e : 0;
    int row = edge_index[ee], col = edge_index[E + ee];
    float wgt = edge_weight[ee];
    float cv = 0.5f * (__cosf(wgt * 0.6283185307179586f) + 1.0f);
    cv = (wgt < 5.0f) ? cv : 0.0f;
    if (valid) cvA[e] = cv;

    float in[48];
    const float4* ap = (const float4*)(edge_attr + (size_t)ee * 32);
#pragma unroll
    for (int i = 0; i < 8; ++i) {
        float4 v = ap[i];
        in[4 * i] = v.x; in[4 * i + 1] = v.y; in[4 * i + 2] = v.z; in[4 * i + 3] = v.w;
    }
    const float4* qr = (const float4*)(charges + (size_t)row * 8);
    float4 q0 = qr[0], q1 = qr[1];
    in[32] = q0.x; in[33] = q0.y; in[34] = q0.z; in[35] = q0.w;
    in[36] = q1.x; in[37] = q1.y; in[38] = q1.z; in[39] = q1.w;
    const float4* qc = (const float4*)(charges + (size_t)col * 8);
    float4 q2 = qc[0], q3 = qc[1];
    in[40] = q2.x; in[41] = q2.y; in[42] = q2.z; in[43] = q2.w;
    in[44] = q3.x; in[45] = q3.y; in[46] = q3.z; in[47] = q3.w;

    for (int c0 = 0; c0 < 64; c0 += 32) {
        float a[32];
#pragma unroll
        for (int c = 0; c < 32; ++c) a[c] = bs1[c0 + c];
#pragma unroll
        for (int k = 0; k < 48; ++k) {
            float xk = in[k];
#pragma unroll
            for (int c = 0; c < 32; ++c) a[c] += xk * Ws1[k * 64 + c0 + c];
        }
        if (valid) {
#pragma unroll
            for (int c = 0; c < 32; ++c) h1g[(size_t)e * 64 + c0 + c] = silu_f(a[c]);
        }
    }
}

// ---------------- MLP layer 2: wave = edge stream, lane = 2 channels --------
__global__ __launch_bounds__(256) void mlp_l2(
    const float* __restrict__ h1g,
    const float* __restrict__ Ws2, const float* __restrict__ bs2,
    float* __restrict__ h2g, int E, int nwaves)
{
    int lane = threadIdx.x & 63;
    int wave = (blockIdx.x * 256 + threadIdx.x) >> 6;
    float wa[64], wb[64];
#pragma unroll
    for (int k = 0; k < 64; ++k) {
        wa[k] = Ws2[k * 128 + lane];
        wb[k] = Ws2[k * 128 + 64 + lane];
    }
    float b0 = bs2[lane], b1 = bs2[64 + lane];
    int per = (E + nwaves - 1) / nwaves;
    int e0 = wave * per;
    int e1 = min(E, e0 + per);
    for (int e = e0; e < e1; ++e) {
        const float* hp = h1g + (size_t)e * 64;
        float a0 = b0, a1 = b1, a2 = 0.f, a3 = 0.f;
#pragma unroll
        for (int k = 0; k < 64; k += 2) {
            float h0 = hp[k], h1v = hp[k + 1];
            a0 += h0 * wa[k];
            a1 += h0 * wb[k];
            a2 += h1v * wa[k + 1];
            a3 += h1v * wb[k + 1];
        }
        h2g[(size_t)e * 128 + lane] = silu_f(a0 + a2);
        h2g[(size_t)e * 128 + 64 + lane] = silu_f(a1 + a3);
    }
}

// ---------------- msg kernel: fused layer-3 + gather + accumulate -----------
// block = node, 3 waves (ct = 0:I, 1:A, 2:S), lane = channel.
__global__ __launch_bounds__(192) void msg_kernel(
    const float* __restrict__ h2g,
    const float* __restrict__ Ws3, const float* __restrict__ bs3,
    const float* __restrict__ cvA, const int* __restrict__ order,
    const int* __restrict__ offs, const int* __restrict__ edge_index,
    const float* __restrict__ Tn, float* __restrict__ Mn, int E)
{
    int n = blockIdx.x;
    int ct = threadIdx.x >> 6;
    int lane = threadIdx.x & 63;
    float wcol[128];
#pragma unroll
    for (int k = 0; k < 128; ++k) wcol[k] = Ws3[k * 192 + ct * 64 + lane];
    float bias = bs3[ct * 64 + lane];
    int beg = offs[n], end = offs[n + 1];
    float acc0 = 0.f, acc1 = 0.f, acc2 = 0.f, acc3 = 0.f, acc4 = 0.f, acc5 = 0.f;
    for (int idx = beg; idx < end; ++idx) {
        int e = order[idx];
        int c = edge_index[E + e];
        const float* hp = h2g + (size_t)e * 128;
        float a0 = bias, a1 = 0.f, a2 = 0.f, a3 = 0.f;
#pragma unroll
        for (int k = 0; k < 128; k += 4) {
            a0 += hp[k] * wcol[k];
            a1 += hp[k + 1] * wcol[k + 1];
            a2 += hp[k + 2] * wcol[k + 2];
            a3 += hp[k + 3] * wcol[k + 3];
        }
        float wv = silu_f((a0 + a1) + (a2 + a3)) * cvA[e];
        const float* tp = Tn + (size_t)c * 640;
        if (ct == 0) {
            acc0 += wv * tp[lane];
        } else if (ct == 1) {
            acc0 += wv * tp[64 + lane];
            acc1 += wv * tp[128 + lane];
            acc2 += wv * tp[192 + lane];
        } else {
            acc0 += wv * tp[256 + lane];
            acc1 += wv * tp[320 + lane];
            acc2 += wv * tp[384 + lane];
            acc3 += wv * tp[448 + lane];
            acc4 += wv * tp[512 + lane];
            acc5 += wv * tp[576 + lane];
        }
    }
    float* mp = Mn + (size_t)n * 640;
    if (ct == 0) {
        mp[lane] = acc0;
    } else if (ct == 1) {
        mp[64 + lane] = acc0; mp[128 + lane] = acc1; mp[192 + lane] = acc2;
    } else {
        mp[256 + lane] = acc0; mp[320 + lane] = acc1; mp[384 + lane] = acc2;
        mp[448 + lane] = acc3; mp[512 + lane] = acc4; mp[576 + lane] = acc5;
    }
}

// ---------------- node_post --------------------------------------------------
__global__ __launch_bounds__(64) void node_post(
    const float* __restrict__ X,
    const float* __restrict__ Tn, const float* __restrict__ Mn,
    const float* __restrict__ Wt3, const float* __restrict__ Wt4, const float* __restrict__ Wt5,
    float* __restrict__ out)
{
    int n = blockIdx.x, h = threadIdx.x;
    // recompute normalized X
    const float* Xb = X + (size_t)n * 9 * HD + h;
    float x[9];
    float nr = 0.f;
#pragma unroll
    for (int i = 0; i < 9; ++i) { x[i] = Xb[i * HD]; nr += x[i] * x[i]; }
    float xinv = 1.0f / (nr + 1.0f);
#pragma unroll
    for (int i = 0; i < 9; ++i) x[i] *= xinv;

    const float* tp = Tn + (size_t)n * 640 + h;
    const float* mp = Mn + (size_t)n * 640 + h;
    float yI = tp[0], mI = mp[0];
    float yA[3], yS[6], mA[3], mS[6];
#pragma unroll
    for (int j = 0; j < 3; ++j) { yA[j] = tp[(1 + j) * 64]; mA[j] = mp[(1 + j) * 64]; }
#pragma unroll
    for (int j = 0; j < 6; ++j) { yS[j] = tp[(4 + j) * 64]; mS[j] = mp[(4 + j) * 64]; }

    float M[3][3] = {
        { mI + mS[0],     mA[0] + mS[1],   mA[1] + mS[2] },
        { -mA[0] + mS[1], mI + mS[3],      mA[2] + mS[4] },
        { -mA[1] + mS[2], -mA[2] + mS[4],  mI + mS[5] } };
    float Y[3][3] = {
        { yI + yS[0],     yA[0] + yS[1],   yA[1] + yS[2] },
        { -yA[0] + yS[1], yI + yS[3],      yA[2] + yS[4] },
        { -yA[1] + yS[2], -yA[2] + yS[4],  yI + yS[5] } };

    float Cm[3][3];
    float nrm = 0.f;
#pragma unroll
    for (int a = 0; a < 3; ++a) {
#pragma unroll
        for (int b = 0; b < 3; ++b) {
            float s = 0.f;
#pragma unroll
            for (int c = 0; c < 3; ++c) s += M[a][c] * Y[c][b] + Y[a][c] * M[c][b];
            Cm[a][b] = s;
            nrm += s * s;
        }
    }
    float inv = 1.0f / (nrm + 1.0f);
    float tr3 = (Cm[0][0] + Cm[1][1] + Cm[2][2]) * (1.0f / 3.0f);

    __shared__ float comp[10][HD];
    comp[0][h] = tr3 * inv;
    comp[1][h] = 0.5f * (Cm[0][1] - Cm[1][0]) * inv;
    comp[2][h] = 0.5f * (Cm[0][2] - Cm[2][0]) * inv;
    comp[3][h] = 0.5f * (Cm[1][2] - Cm[2][1]) * inv;
    comp[4][h] = (Cm[0][0] - tr3) * inv;
    comp[5][h] = 0.5f * (Cm[0][1] + Cm[1][0]) * inv;
    comp[6][h] = 0.5f * (Cm[0][2] + Cm[2][0]) * inv;
    comp[7][h] = (Cm[1][1] - tr3) * inv;
    comp[8][h] = 0.5f * (Cm[1][2] + Cm[2][1]) * inv;
    comp[9][h] = (Cm[2][2] - tr3) * inv;
    __syncthreads();

    float acc[10];
#pragma unroll
    for (int i = 0; i < 10; ++i) acc[i] = 0.f;
    for (int k = 0; k < HD; ++k) {
        float w3 = Wt3[k * HD + h];
        float w4 = Wt4[k * HD + h];
        float w5 = Wt5[k * HD + h];
        acc[0] += comp[0][k] * w3;
        acc[1] += comp[1][k] * w4;
        acc[2] += comp[2][k] * w4;
        acc[3] += comp[3][k] * w4;
#pragma unroll
        for (int j = 0; j < 6; ++j) acc[4 + j] += comp[4 + j][k] * w5;
    }
    float D[3][3] = {
        { acc[0] + acc[4],  acc[1] + acc[5],  acc[2] + acc[6] },
        { -acc[1] + acc[5], acc[0] + acc[7],  acc[3] + acc[8] },
        { -acc[2] + acc[6], -acc[3] + acc[8], acc[0] + acc[9] } };

    float* ob = out + (size_t)n * 9 * HD + h;
#pragma unroll
    for (int a = 0; a < 3; ++a) {
#pragma unroll
        for (int b = 0; b < 3; ++b) {
            float s = 0.f;
#pragma unroll
            for (int c = 0; c < 3; ++c) s += D[a][c] * D[c][b];
            ob[(a * 3 + b) * HD] = x[a * 3 + b] + D[a][b] + s;
        }
    }
}

// ---------------- launch ------------------------------------------------------
extern "C" void kernel_launch(void* const* d_in, const int* in_sizes, int n_in,
                              void* d_out, int out_size, void* d_ws, size_t ws_size,
                              hipStream_t stream)
{
    const float* X           = (const float*)d_in[0];
    const float* charges     = (const float*)d_in[1];
    const float* edge_weight = (const float*)d_in[2];
    const float* edge_attr   = (const float*)d_in[3];
    const int*   edge_index  = (const int*)d_in[4];
    const float* Ws1 = (const float*)d_in[5];
    const float* bs1 = (const float*)d_in[6];
    const float* Ws2 = (const float*)d_in[7];
    const float* bs2 = (const float*)d_in[8];
    const float* Ws3 = (const float*)d_in[9];
    const float* bs3 = (const float*)d_in[10];
    const float* Wt0 = (const float*)d_in[11];
    const float* Wt1 = (const float*)d_in[12];
    const float* Wt2 = (const float*)d_in[13];
    const float* Wt3 = (const float*)d_in[14];
    const float* Wt4 = (const float*)d_in[15];
    const float* Wt5 = (const float*)d_in[16];

    int N = in_sizes[0] / (9 * HD);
    int E = in_sizes[2];

    float* ws = (float*)d_ws;
    float* Tn  = ws;                              // N*10*64
    float* Mn  = Tn + (size_t)N * 640;            // N*10*64
    float* h1g = Mn + (size_t)N * 640;            // E*64
    float* h2g = h1g + (size_t)E * 64;            // E*128
    float* cvA = h2g + (size_t)E * 128;           // E
    int* cnt   = (int*)(cvA + E);                 // N
    int* offs  = cnt + N;                         // N+1
    int* curs  = offs + N + 1;                    // N
    int* order = curs + N;                        // E

    hipMemsetAsync(cnt, 0, (size_t)N * sizeof(int), stream);

    node_pre<<<N, 64, 0, stream>>>(X, Wt0, Wt1, Wt2, Tn);

    int nbE = (E + 255) / 256;
    count_kernel<<<nbE, 256, 0, stream>>>(edge_index, cnt, E);
    scan_kernel<<<1, 1024, 0, stream>>>(cnt, offs, curs, N);
    place_kernel<<<nbE, 256, 0, stream>>>(edge_index, curs, order, E);

    mlp_l1<<<nbE, 256, 0, stream>>>(edge_attr, charges, edge_weight, edge_index,
                                    Ws1, bs1, h1g, cvA, E);

    int nbL2 = 768;
    int nwaves = nbL2 * 4;
    mlp_l2<<<nbL2, 256, 0, stream>>>(h1g, Ws2, bs2, h2g, E, nwaves);

    msg_kernel<<<N, 192, 0, stream>>>(h2g, Ws3, bs3, cvA, order, offs,
                                      edge_index, Tn, Mn, E);

    node_post<<<N, 64, 0, stream>>>(X, Tn, Mn, Wt3, Wt4, Wt5, (float*)d_out);
}

// Round 3
// 559.608 us; speedup vs baseline: 5.6707x; 1.1319x over previous
//
#include <hip/hip_runtime.h>
#include <math.h>

#define HD 64

__device__ __forceinline__ float silu_f(float x) {
    return x / (1.0f + __expf(-x));
}

// ---------------- node_pre: normalize, decompose, Wt0/1/2 -> Tn[n][10][64] --
__global__ __launch_bounds__(64) void node_pre(
    const float* __restrict__ X,
    const float* __restrict__ Wt0, const float* __restrict__ Wt1, const float* __restrict__ Wt2,
    float* __restrict__ Tn)
{
    int n = blockIdx.x;
    int h = threadIdx.x;
    const float* Xb = X + (size_t)n * 9 * HD + h;
    float x[9];
    float nrm = 0.f;
#pragma unroll
    for (int i = 0; i < 9; ++i) { x[i] = Xb[i * HD]; nrm += x[i] * x[i]; }
    float inv = 1.0f / (nrm + 1.0f);
#pragma unroll
    for (int i = 0; i < 9; ++i) x[i] *= inv;

    float I0 = (x[0] + x[4] + x[8]) * (1.0f / 3.0f);
    __shared__ float comp[10][HD];
    comp[0][h] = I0;
    comp[1][h] = 0.5f * (x[1] - x[3]);
    comp[2][h] = 0.5f * (x[2] - x[6]);
    comp[3][h] = 0.5f * (x[5] - x[7]);
    comp[4][h] = x[0] - I0;
    comp[5][h] = 0.5f * (x[1] + x[3]);
    comp[6][h] = 0.5f * (x[2] + x[6]);
    comp[7][h] = x[4] - I0;
    comp[8][h] = 0.5f * (x[5] + x[7]);
    comp[9][h] = x[8] - I0;
    __syncthreads();
    float acc[10];
#pragma unroll
    for (int i = 0; i < 10; ++i) acc[i] = 0.f;
    for (int k = 0; k < HD; ++k) {
        float w0 = Wt0[k * HD + h];
        float w1 = Wt1[k * HD + h];
        float w2 = Wt2[k * HD + h];
        acc[0] += comp[0][k] * w0;
        acc[1] += comp[1][k] * w1;
        acc[2] += comp[2][k] * w1;
        acc[3] += comp[3][k] * w1;
#pragma unroll
        for (int j = 0; j < 6; ++j) acc[4 + j] += comp[4 + j][k] * w2;
    }
    float* tp = Tn + (size_t)n * 640 + h;
#pragma unroll
    for (int i = 0; i < 10; ++i) tp[i * 64] = acc[i];
}

// ---------------- CSR build --------------------------------------------------
__global__ __launch_bounds__(256) void count_kernel(
    const int* __restrict__ edge_index, int* __restrict__ cnt, int E)
{
    int e = blockIdx.x * 256 + threadIdx.x;
    if (e < E) atomicAdd(&cnt[edge_index[e]], 1);
}

__global__ __launch_bounds__(1024) void scan_kernel(
    const int* __restrict__ cnt, int* __restrict__ offs, int* __restrict__ curs, int N)
{
    __shared__ int lds[1024];
    __shared__ int base_s;
    int tid = threadIdx.x;
    if (tid == 0) base_s = 0;
    __syncthreads();
    for (int start = 0; start < N; start += 1024) {
        int i = start + tid;
        int v = (i < N) ? cnt[i] : 0;
        lds[tid] = v;
        __syncthreads();
        for (int off = 1; off < 1024; off <<= 1) {
            int t = (tid >= off) ? lds[tid - off] : 0;
            __syncthreads();
            lds[tid] += t;
            __syncthreads();
        }
        int base = base_s;
        int excl = base + lds[tid] - v;
        if (i < N) { offs[i] = excl; curs[i] = excl; }
        __syncthreads();
        if (tid == 1023) base_s = base + lds[1023];
        __syncthreads();
    }
    if (tid == 0) offs[N] = base_s;
}

__global__ __launch_bounds__(256) void place_kernel(
    const int* __restrict__ edge_index, int* __restrict__ curs, int* __restrict__ order, int E)
{
    int e = blockIdx.x * 256 + threadIdx.x;
    if (e < E) {
        int p = atomicAdd(&curs[edge_index[e]], 1);
        order[p] = e;
    }
}

// ---------------- MLP layer 1: lane = edge, 48 -> 64 -------------------------
// inputs staged in LDS (padded row 49 -> conflict-free), weights uniform float4,
// acc[64] static registers. Writes silu(h1) into buf[e*192 + 128 .. 192).
__global__ __launch_bounds__(64) void mlp_l1(
    const float* __restrict__ edge_attr, const float* __restrict__ charges,
    const float* __restrict__ edge_weight, const int* __restrict__ edge_index,
    const float* __restrict__ Ws1, const float* __restrict__ bs1,
    float* __restrict__ buf, float* __restrict__ cvA, int E)
{
    __shared__ float ins[64][49];
    int lane = threadIdx.x;
    int e = blockIdx.x * 64 + lane;
    bool valid = (e < E);
    int ee = valid ? e : (E - 1);

    int row = edge_index[ee], col = edge_index[E + ee];
    float wgt = edge_weight[ee];
    float cv = 0.5f * (__cosf(wgt * 0.6283185307179586f) + 1.0f);
    cv = (wgt < 5.0f) ? cv : 0.0f;
    if (valid) cvA[e] = cv;

    const float4* ap = (const float4*)(edge_attr + (size_t)ee * 32);
#pragma unroll
    for (int i = 0; i < 8; ++i) {
        float4 v = ap[i];
        ins[lane][4 * i + 0] = v.x; ins[lane][4 * i + 1] = v.y;
        ins[lane][4 * i + 2] = v.z; ins[lane][4 * i + 3] = v.w;
    }
    const float4* qr = (const float4*)(charges + (size_t)row * 8);
    float4 q0 = qr[0], q1 = qr[1];
    ins[lane][32] = q0.x; ins[lane][33] = q0.y; ins[lane][34] = q0.z; ins[lane][35] = q0.w;
    ins[lane][36] = q1.x; ins[lane][37] = q1.y; ins[lane][38] = q1.z; ins[lane][39] = q1.w;
    const float4* qc = (const float4*)(charges + (size_t)col * 8);
    float4 q2 = qc[0], q3 = qc[1];
    ins[lane][40] = q2.x; ins[lane][41] = q2.y; ins[lane][42] = q2.z; ins[lane][43] = q2.w;
    ins[lane][44] = q3.x; ins[lane][45] = q3.y; ins[lane][46] = q3.z; ins[lane][47] = q3.w;

    float acc[64];
#pragma unroll
    for (int c = 0; c < 64; c += 4) {
        float4 b = *(const float4*)(bs1 + c);
        acc[c] = b.x; acc[c + 1] = b.y; acc[c + 2] = b.z; acc[c + 3] = b.w;
    }
    for (int k = 0; k < 48; ++k) {
        float xk = ins[lane][k];
#pragma unroll
        for (int c = 0; c < 64; c += 4) {
            float4 w = *(const float4*)(Ws1 + k * 64 + c);
            acc[c]     += xk * w.x;
            acc[c + 1] += xk * w.y;
            acc[c + 2] += xk * w.z;
            acc[c + 3] += xk * w.w;
        }
    }
    if (valid) {
        float* hp = buf + (size_t)e * 192 + 128;
#pragma unroll
        for (int c = 0; c < 64; c += 4) {
            float4 o;
            o.x = silu_f(acc[c]); o.y = silu_f(acc[c + 1]);
            o.z = silu_f(acc[c + 2]); o.w = silu_f(acc[c + 3]);
            *(float4*)(hp + c) = o;
        }
    }
}

// ---------------- MLP layer 2: lane = edge, 64 -> 128 ------------------------
// reads h1 from buf[e*192+128..192) (L1/L2 tile), writes h2 to buf[e*192+0..128).
__global__ __launch_bounds__(64) void mlp_l2(
    const float* __restrict__ Ws2, const float* __restrict__ bs2,
    float* __restrict__ buf, int E)
{
    int e = blockIdx.x * 64 + threadIdx.x;
    if (e >= E) return;
    const float* hp = buf + (size_t)e * 192 + 128;
    for (int cc = 0; cc < 4; ++cc) {
        float acc[32];
#pragma unroll
        for (int j = 0; j < 32; j += 4) {
            float4 b = *(const float4*)(bs2 + cc * 32 + j);
            acc[j] = b.x; acc[j + 1] = b.y; acc[j + 2] = b.z; acc[j + 3] = b.w;
        }
        for (int k = 0; k < 64; ++k) {
            float xk = hp[k];
#pragma unroll
            for (int j = 0; j < 32; j += 4) {
                float4 w = *(const float4*)(Ws2 + k * 128 + cc * 32 + j);
                acc[j]     += xk * w.x;
                acc[j + 1] += xk * w.y;
                acc[j + 2] += xk * w.z;
                acc[j + 3] += xk * w.w;
            }
        }
        float* op = buf + (size_t)e * 192 + cc * 32;
#pragma unroll
        for (int j = 0; j < 32; j += 4) {
            float4 o;
            o.x = silu_f(acc[j]); o.y = silu_f(acc[j + 1]);
            o.z = silu_f(acc[j + 2]); o.w = silu_f(acc[j + 3]);
            *(float4*)(op + j) = o;
        }
    }
}

// ---------------- MLP layer 3: lane = edge, 128 -> 192, in-place -------------
// reads h2 from buf[e*192 + 0..128), overwrites buf[e*192 + 0..192) with
// w = silu(h2 @ Ws3 + bs3) * cv. acc[192] static registers (~2 waves/SIMD,
// ILP=192 keeps the FMA pipe full).
__global__ __launch_bounds__(64) void mlp_l3(
    const float* __restrict__ Ws3, const float* __restrict__ bs3,
    const float* __restrict__ cvA, float* __restrict__ buf, int E)
{
    int e = blockIdx.x * 64 + threadIdx.x;
    if (e >= E) return;
    const float* hp = buf + (size_t)e * 192;
    float acc[192];
#pragma unroll
    for (int j = 0; j < 192; j += 4) {
        float4 b = *(const float4*)(bs3 + j);
        acc[j] = b.x; acc[j + 1] = b.y; acc[j + 2] = b.z; acc[j + 3] = b.w;
    }
#pragma unroll 2
    for (int k = 0; k < 128; ++k) {
        float xk = hp[k];
#pragma unroll
        for (int j = 0; j < 192; j += 4) {
            float4 w = *(const float4*)(Ws3 + k * 192 + j);
            acc[j]     += xk * w.x;
            acc[j + 1] += xk * w.y;
            acc[j + 2] += xk * w.z;
            acc[j + 3] += xk * w.w;
        }
    }
    float cv = cvA[e];
    float* op = buf + (size_t)e * 192;
#pragma unroll
    for (int j = 0; j < 192; j += 4) {
        float4 o;
        o.x = silu_f(acc[j]) * cv;
        o.y = silu_f(acc[j + 1]) * cv;
        o.z = silu_f(acc[j + 2]) * cv;
        o.w = silu_f(acc[j + 3]) * cv;
        *(float4*)(op + j) = o;
    }
}

// ---------------- msg kernel: pure gather + accumulate -----------------------
// block = node (1 wave), lane = channel. Per edge: 3 coalesced w loads,
// 10 coalesced Tn loads, 10 FMAs. No layer-3 recompute, no atomics.
__global__ __launch_bounds__(64) void msg_kernel(
    const float* __restrict__ buf, const int* __restrict__ order,
    const int* __restrict__ offs, const int* __restrict__ edge_index,
    const float* __restrict__ Tn, float* __restrict__ Mn, int E)
{
    int n = blockIdx.x;
    int lane = threadIdx.x;
    int beg = offs[n], end = offs[n + 1];
    float a0 = 0.f, a1 = 0.f, a2 = 0.f, a3 = 0.f, a4 = 0.f;
    float a5 = 0.f, a6 = 0.f, a7 = 0.f, a8 = 0.f, a9 = 0.f;
#pragma unroll 2
    for (int idx = beg; idx < end; ++idx) {
        int e = order[idx];
        int c = edge_index[E + e];
        const float* wp = buf + (size_t)e * 192;
        float w0 = wp[lane];
        float w1 = wp[64 + lane];
        float w2 = wp[128 + lane];
        const float* tp = Tn + (size_t)c * 640;
        a0 += w0 * tp[lane];
        a1 += w1 * tp[64 + lane];
        a2 += w1 * tp[128 + lane];
        a3 += w1 * tp[192 + lane];
        a4 += w2 * tp[256 + lane];
        a5 += w2 * tp[320 + lane];
        a6 += w2 * tp[384 + lane];
        a7 += w2 * tp[448 + lane];
        a8 += w2 * tp[512 + lane];
        a9 += w2 * tp[576 + lane];
    }
    float* mp = Mn + (size_t)n * 640;
    mp[lane] = a0;
    mp[64 + lane] = a1;  mp[128 + lane] = a2; mp[192 + lane] = a3;
    mp[256 + lane] = a4; mp[320 + lane] = a5; mp[384 + lane] = a6;
    mp[448 + lane] = a7; mp[512 + lane] = a8; mp[576 + lane] = a9;
}

// ---------------- node_post --------------------------------------------------
__global__ __launch_bounds__(64) void node_post(
    const float* __restrict__ X,
    const float* __restrict__ Tn, const float* __restrict__ Mn,
    const float* __restrict__ Wt3, const float* __restrict__ Wt4, const float* __restrict__ Wt5,
    float* __restrict__ out)
{
    int n = blockIdx.x, h = threadIdx.x;
    const float* Xb = X + (size_t)n * 9 * HD + h;
    float x[9];
    float nr = 0.f;
#pragma unroll
    for (int i = 0; i < 9; ++i) { x[i] = Xb[i * HD]; nr += x[i] * x[i]; }
    float xinv = 1.0f / (nr + 1.0f);
#pragma unroll
    for (int i = 0; i < 9; ++i) x[i] *= xinv;

    const float* tp = Tn + (size_t)n * 640 + h;
    const float* mp = Mn + (size_t)n * 640 + h;
    float yI = tp[0], mI = mp[0];
    float yA[3], yS[6], mA[3], mS[6];
#pragma unroll
    for (int j = 0; j < 3; ++j) { yA[j] = tp[(1 + j) * 64]; mA[j] = mp[(1 + j) * 64]; }
#pragma unroll
    for (int j = 0; j < 6; ++j) { yS[j] = tp[(4 + j) * 64]; mS[j] = mp[(4 + j) * 64]; }

    float M[3][3] = {
        { mI + mS[0],     mA[0] + mS[1],   mA[1] + mS[2] },
        { -mA[0] + mS[1], mI + mS[3],      mA[2] + mS[4] },
        { -mA[1] + mS[2], -mA[2] + mS[4],  mI + mS[5] } };
    float Y[3][3] = {
        { yI + yS[0],     yA[0] + yS[1],   yA[1] + yS[2] },
        { -yA[0] + yS[1], yI + yS[3],      yA[2] + yS[4] },
        { -yA[1] + yS[2], -yA[2] + yS[4],  yI + yS[5] } };

    float Cm[3][3];
    float nrm = 0.f;
#pragma unroll
    for (int a = 0; a < 3; ++a) {
#pragma unroll
        for (int b = 0; b < 3; ++b) {
            float s = 0.f;
#pragma unroll
            for (int c = 0; c < 3; ++c) s += M[a][c] * Y[c][b] + Y[a][c] * M[c][b];
            Cm[a][b] = s;
            nrm += s * s;
        }
    }
    float inv = 1.0f / (nrm + 1.0f);
    float tr3 = (Cm[0][0] + Cm[1][1] + Cm[2][2]) * (1.0f / 3.0f);

    __shared__ float comp[10][HD];
    comp[0][h] = tr3 * inv;
    comp[1][h] = 0.5f * (Cm[0][1] - Cm[1][0]) * inv;
    comp[2][h] = 0.5f * (Cm[0][2] - Cm[2][0]) * inv;
    comp[3][h] = 0.5f * (Cm[1][2] - Cm[2][1]) * inv;
    comp[4][h] = (Cm[0][0] - tr3) * inv;
    comp[5][h] = 0.5f * (Cm[0][1] + Cm[1][0]) * inv;
    comp[6][h] = 0.5f * (Cm[0][2] + Cm[2][0]) * inv;
    comp[7][h] = (Cm[1][1] - tr3) * inv;
    comp[8][h] = 0.5f * (Cm[1][2] + Cm[2][1]) * inv;
    comp[9][h] = (Cm[2][2] - tr3) * inv;
    __syncthreads();

    float acc[10];
#pragma unroll
    for (int i = 0; i < 10; ++i) acc[i] = 0.f;
    for (int k = 0; k < HD; ++k) {
        float w3 = Wt3[k * HD + h];
        float w4 = Wt4[k * HD + h];
        float w5 = Wt5[k * HD + h];
        acc[0] += comp[0][k] * w3;
        acc[1] += comp[1][k] * w4;
        acc[2] += comp[2][k] * w4;
        acc[3] += comp[3][k] * w4;
#pragma unroll
        for (int j = 0; j < 6; ++j) acc[4 + j] += comp[4 + j][k] * w5;
    }
    float D[3][3] = {
        { acc[0] + acc[4],  acc[1] + acc[5],  acc[2] + acc[6] },
        { -acc[1] + acc[5], acc[0] + acc[7],  acc[3] + acc[8] },
        { -acc[2] + acc[6], -acc[3] + acc[8], acc[0] + acc[9] } };

    float* ob = out + (size_t)n * 9 * HD + h;
#pragma unroll
    for (int a = 0; a < 3; ++a) {
#pragma unroll
        for (int b = 0; b < 3; ++b) {
            float s = 0.f;
#pragma unroll
            for (int c = 0; c < 3; ++c) s += D[a][c] * D[c][b];
            ob[(a * 3 + b) * HD] = x[a * 3 + b] + D[a][b] + s;
        }
    }
}

// ---------------- launch ------------------------------------------------------
extern "C" void kernel_launch(void* const* d_in, const int* in_sizes, int n_in,
                              void* d_out, int out_size, void* d_ws, size_t ws_size,
                              hipStream_t stream)
{
    const float* X           = (const float*)d_in[0];
    const float* charges     = (const float*)d_in[1];
    const float* edge_weight = (const float*)d_in[2];
    const float* edge_attr   = (const float*)d_in[3];
    const int*   edge_index  = (const int*)d_in[4];
    const float* Ws1 = (const float*)d_in[5];
    const float* bs1 = (const float*)d_in[6];
    const float* Ws2 = (const float*)d_in[7];
    const float* bs2 = (const float*)d_in[8];
    const float* Ws3 = (const float*)d_in[9];
    const float* bs3 = (const float*)d_in[10];
    const float* Wt0 = (const float*)d_in[11];
    const float* Wt1 = (const float*)d_in[12];
    const float* Wt2 = (const float*)d_in[13];
    const float* Wt3 = (const float*)d_in[14];
    const float* Wt4 = (const float*)d_in[15];
    const float* Wt5 = (const float*)d_in[16];

    int N = in_sizes[0] / (9 * HD);
    int E = in_sizes[2];

    float* ws = (float*)d_ws;
    float* Tn  = ws;                              // N*640
    float* Mn  = Tn + (size_t)N * 640;            // N*640
    float* buf = Mn + (size_t)N * 640;            // E*192 (h1 tail -> h2 head -> w in place)
    float* cvA = buf + (size_t)E * 192;           // E
    int* cnt   = (int*)(cvA + E);                 // N
    int* offs  = cnt + N;                         // N+1
    int* curs  = offs + N + 1;                    // N
    int* order = curs + N;                        // E

    hipMemsetAsync(cnt, 0, (size_t)N * sizeof(int), stream);

    node_pre<<<N, 64, 0, stream>>>(X, Wt0, Wt1, Wt2, Tn);

    int nbE256 = (E + 255) / 256;
    count_kernel<<<nbE256, 256, 0, stream>>>(edge_index, cnt, E);
    scan_kernel<<<1, 1024, 0, stream>>>(cnt, offs, curs, N);
    place_kernel<<<nbE256, 256, 0, stream>>>(edge_index, curs, order, E);

    int nbE64 = (E + 63) / 64;
    mlp_l1<<<nbE64, 64, 0, stream>>>(edge_attr, charges, edge_weight, edge_index,
                                     Ws1, bs1, buf, cvA, E);
    mlp_l2<<<nbE64, 64, 0, stream>>>(Ws2, bs2, buf, E);
    mlp_l3<<<nbE64, 64, 0, stream>>>(Ws3, bs3, cvA, buf, E);

    msg_kernel<<<N, 64, 0, stream>>>(buf, order, offs, edge_index, Tn, Mn, E);

    node_post<<<N, 64, 0, stream>>>(X, Tn, Mn, Wt3, Wt4, Wt5, (float*)d_out);
}

// Round 4
// 495.206 us; speedup vs baseline: 6.4082x; 1.1301x over previous
//
#include <hip/hip_runtime.h>
#include <math.h>

#define HD 64

__device__ __forceinline__ float silu_f(float x) {
    return x / (1.0f + __expf(-x));
}

// ---------------- node_pre: normalize, decompose, Wt0/1/2 -> Tn[n][10][64] --
__global__ __launch_bounds__(64) void node_pre(
    const float* __restrict__ X,
    const float* __restrict__ Wt0, const float* __restrict__ Wt1, const float* __restrict__ Wt2,
    float* __restrict__ Tn)
{
    int n = blockIdx.x;
    int h = threadIdx.x;
    const float* Xb = X + (size_t)n * 9 * HD + h;
    float x[9];
    float nrm = 0.f;
#pragma unroll
    for (int i = 0; i < 9; ++i) { x[i] = Xb[i * HD]; nrm += x[i] * x[i]; }
    float inv = 1.0f / (nrm + 1.0f);
#pragma unroll
    for (int i = 0; i < 9; ++i) x[i] *= inv;

    float I0 = (x[0] + x[4] + x[8]) * (1.0f / 3.0f);
    __shared__ float comp[10][HD];
    comp[0][h] = I0;
    comp[1][h] = 0.5f * (x[1] - x[3]);
    comp[2][h] = 0.5f * (x[2] - x[6]);
    comp[3][h] = 0.5f * (x[5] - x[7]);
    comp[4][h] = x[0] - I0;
    comp[5][h] = 0.5f * (x[1] + x[3]);
    comp[6][h] = 0.5f * (x[2] + x[6]);
    comp[7][h] = x[4] - I0;
    comp[8][h] = 0.5f * (x[5] + x[7]);
    comp[9][h] = x[8] - I0;
    __syncthreads();
    float acc[10];
#pragma unroll
    for (int i = 0; i < 10; ++i) acc[i] = 0.f;
    for (int k = 0; k < HD; ++k) {
        float w0 = Wt0[k * HD + h];
        float w1 = Wt1[k * HD + h];
        float w2 = Wt2[k * HD + h];
        acc[0] += comp[0][k] * w0;
        acc[1] += comp[1][k] * w1;
        acc[2] += comp[2][k] * w1;
        acc[3] += comp[3][k] * w1;
#pragma unroll
        for (int j = 0; j < 6; ++j) acc[4 + j] += comp[4 + j][k] * w2;
    }
    float* tp = Tn + (size_t)n * 640 + h;
#pragma unroll
    for (int i = 0; i < 10; ++i) tp[i * 64] = acc[i];
}

// ---------------- CSR build --------------------------------------------------
__global__ __launch_bounds__(256) void count_kernel(
    const int* __restrict__ edge_index, int* __restrict__ cnt, int E)
{
    int e = blockIdx.x * 256 + threadIdx.x;
    if (e < E) atomicAdd(&cnt[edge_index[e]], 1);
}

__global__ __launch_bounds__(1024) void scan_kernel(
    const int* __restrict__ cnt, int* __restrict__ offs, int* __restrict__ curs, int N)
{
    __shared__ int lds[1024];
    __shared__ int base_s;
    int tid = threadIdx.x;
    if (tid == 0) base_s = 0;
    __syncthreads();
    for (int start = 0; start < N; start += 1024) {
        int i = start + tid;
        int v = (i < N) ? cnt[i] : 0;
        lds[tid] = v;
        __syncthreads();
        for (int off = 1; off < 1024; off <<= 1) {
            int t = (tid >= off) ? lds[tid - off] : 0;
            __syncthreads();
            lds[tid] += t;
            __syncthreads();
        }
        int base = base_s;
        int excl = base + lds[tid] - v;
        if (i < N) { offs[i] = excl; curs[i] = excl; }
        __syncthreads();
        if (tid == 1023) base_s = base + lds[1023];
        __syncthreads();
    }
    if (tid == 0) offs[N] = base_s;
}

__global__ __launch_bounds__(256) void place_kernel(
    const int* __restrict__ edge_index, int* __restrict__ curs, int* __restrict__ order, int E)
{
    int e = blockIdx.x * 256 + threadIdx.x;
    if (e < E) {
        int p = atomicAdd(&curs[edge_index[e]], 1);
        order[p] = e;
    }
}

// ---------------- MLP layers 1+2 fused: lane = edge, 48 -> 64 -> 128 ---------
// Per-lane LDS row (padded to 65 -> bank-conflict-free) serves as a
// runtime-indexable local array for inputs then h1. h1 never touches HBM.
// acc arrays statically indexed; __launch_bounds__(64,2) -> 256-VGPR cap,
// no spill (max live ~160).
__global__ __launch_bounds__(64, 2) void mlp_l12(
    const float* __restrict__ edge_attr, const float* __restrict__ charges,
    const float* __restrict__ edge_weight, const int* __restrict__ edge_index,
    const float* __restrict__ Ws1, const float* __restrict__ bs1,
    const float* __restrict__ Ws2, const float* __restrict__ bs2,
    float* __restrict__ buf, float* __restrict__ cvA, int E)
{
    __shared__ float lds[64][65];
    int lane = threadIdx.x;
    int e = blockIdx.x * 64 + lane;
    bool valid = (e < E);
    int ee = valid ? e : (E - 1);

    int row = edge_index[ee], col = edge_index[E + ee];
    float wgt = edge_weight[ee];
    float cv = 0.5f * (__cosf(wgt * 0.6283185307179586f) + 1.0f);
    cv = (wgt < 5.0f) ? cv : 0.0f;
    if (valid) cvA[e] = cv;

    // stage inputs into own LDS row
    const float4* ap = (const float4*)(edge_attr + (size_t)ee * 32);
#pragma unroll
    for (int i = 0; i < 8; ++i) {
        float4 v = ap[i];
        lds[lane][4 * i + 0] = v.x; lds[lane][4 * i + 1] = v.y;
        lds[lane][4 * i + 2] = v.z; lds[lane][4 * i + 3] = v.w;
    }
    {
        const float4* qr = (const float4*)(charges + (size_t)row * 8);
        float4 q0 = qr[0], q1 = qr[1];
        lds[lane][32] = q0.x; lds[lane][33] = q0.y; lds[lane][34] = q0.z; lds[lane][35] = q0.w;
        lds[lane][36] = q1.x; lds[lane][37] = q1.y; lds[lane][38] = q1.z; lds[lane][39] = q1.w;
        const float4* qc = (const float4*)(charges + (size_t)col * 8);
        float4 q2 = qc[0], q3 = qc[1];
        lds[lane][40] = q2.x; lds[lane][41] = q2.y; lds[lane][42] = q2.z; lds[lane][43] = q2.w;
        lds[lane][44] = q3.x; lds[lane][45] = q3.y; lds[lane][46] = q3.z; lds[lane][47] = q3.w;
    }

    // ---- layer 1: 48 -> 64 ----
    float acc1[64];
#pragma unroll
    for (int c = 0; c < 64; c += 4) {
        float4 b = *(const float4*)(bs1 + c);
        acc1[c] = b.x; acc1[c + 1] = b.y; acc1[c + 2] = b.z; acc1[c + 3] = b.w;
    }
    for (int k = 0; k < 48; ++k) {
        float xk = lds[lane][k];
#pragma unroll
        for (int c = 0; c < 64; c += 4) {
            float4 w = *(const float4*)(Ws1 + k * 64 + c);
            acc1[c]     += xk * w.x;
            acc1[c + 1] += xk * w.y;
            acc1[c + 2] += xk * w.z;
            acc1[c + 3] += xk * w.w;
        }
    }
    // h1 back into own LDS row (reads of ins all done; same lane, no barrier)
#pragma unroll
    for (int c = 0; c < 64; ++c) lds[lane][c] = silu_f(acc1[c]);

    // ---- layer 2: 64 -> 128 ----
    float acc2[128];
#pragma unroll
    for (int c = 0; c < 128; c += 4) {
        float4 b = *(const float4*)(bs2 + c);
        acc2[c] = b.x; acc2[c + 1] = b.y; acc2[c + 2] = b.z; acc2[c + 3] = b.w;
    }
    for (int k = 0; k < 64; ++k) {
        float xk = lds[lane][k];
#pragma unroll
        for (int c = 0; c < 128; c += 4) {
            float4 w = *(const float4*)(Ws2 + k * 128 + c);
            acc2[c]     += xk * w.x;
            acc2[c + 1] += xk * w.y;
            acc2[c + 2] += xk * w.z;
            acc2[c + 3] += xk * w.w;
        }
    }
    if (valid) {
        float* hp = buf + (size_t)e * 192;   // h2 at row head
#pragma unroll
        for (int c = 0; c < 128; c += 4) {
            float4 o;
            o.x = silu_f(acc2[c]);     o.y = silu_f(acc2[c + 1]);
            o.z = silu_f(acc2[c + 2]); o.w = silu_f(acc2[c + 3]);
            *(float4*)(hp + c) = o;
        }
    }
}

// ---------------- MLP layer 3: lane = edge, 128 -> 192, in-place -------------
// Chunk A: outputs [128,192) with acc[64] -> written to the dead h1 region.
// Chunk B: outputs [0,128) with acc[128]  -> overwrites h2 after all reads
// (per-lane sequential, same row -> safe). Max live acc = 128, no spill.
__global__ __launch_bounds__(64, 2) void mlp_l3(
    const float* __restrict__ Ws3, const float* __restrict__ bs3,
    const float* __restrict__ cvA, float* __restrict__ buf, int E)
{
    int e = blockIdx.x * 64 + threadIdx.x;
    if (e >= E) return;
    float* rp = buf + (size_t)e * 192;
    float cv = cvA[e];

    // ---- chunk A: outputs 128..191 ----
    {
        float acc[64];
#pragma unroll
        for (int j = 0; j < 64; j += 4) {
            float4 b = *(const float4*)(bs3 + 128 + j);
            acc[j] = b.x; acc[j + 1] = b.y; acc[j + 2] = b.z; acc[j + 3] = b.w;
        }
        for (int k = 0; k < 128; ++k) {
            float xk = rp[k];
#pragma unroll
            for (int j = 0; j < 64; j += 4) {
                float4 w = *(const float4*)(Ws3 + k * 192 + 128 + j);
                acc[j]     += xk * w.x;
                acc[j + 1] += xk * w.y;
                acc[j + 2] += xk * w.z;
                acc[j + 3] += xk * w.w;
            }
        }
#pragma unroll
        for (int j = 0; j < 64; j += 4) {
            float4 o;
            o.x = silu_f(acc[j]) * cv;     o.y = silu_f(acc[j + 1]) * cv;
            o.z = silu_f(acc[j + 2]) * cv; o.w = silu_f(acc[j + 3]) * cv;
            *(float4*)(rp + 128 + j) = o;
        }
    }

    // ---- chunk B: outputs 0..127 (reads h2 fully, then overwrites it) ----
    {
        float acc[128];
#pragma unroll
        for (int j = 0; j < 128; j += 4) {
            float4 b = *(const float4*)(bs3 + j);
            acc[j] = b.x; acc[j + 1] = b.y; acc[j + 2] = b.z; acc[j + 3] = b.w;
        }
        for (int k = 0; k < 128; ++k) {
            float xk = rp[k];
#pragma unroll
            for (int j = 0; j < 128; j += 4) {
                float4 w = *(const float4*)(Ws3 + k * 192 + j);
                acc[j]     += xk * w.x;
                acc[j + 1] += xk * w.y;
                acc[j + 2] += xk * w.z;
                acc[j + 3] += xk * w.w;
            }
        }
#pragma unroll
        for (int j = 0; j < 128; j += 4) {
            float4 o;
            o.x = silu_f(acc[j]) * cv;     o.y = silu_f(acc[j + 1]) * cv;
            o.z = silu_f(acc[j + 2]) * cv; o.w = silu_f(acc[j + 3]) * cv;
            *(float4*)(rp + j) = o;
        }
    }
}

// ---------------- msg kernel: pure gather + accumulate -----------------------
__global__ __launch_bounds__(64) void msg_kernel(
    const float* __restrict__ buf, const int* __restrict__ order,
    const int* __restrict__ offs, const int* __restrict__ edge_index,
    const float* __restrict__ Tn, float* __restrict__ Mn, int E)
{
    int n = blockIdx.x;
    int lane = threadIdx.x;
    int beg = offs[n], end = offs[n + 1];
    float a0 = 0.f, a1 = 0.f, a2 = 0.f, a3 = 0.f, a4 = 0.f;
    float a5 = 0.f, a6 = 0.f, a7 = 0.f, a8 = 0.f, a9 = 0.f;
#pragma unroll 2
    for (int idx = beg; idx < end; ++idx) {
        int e = order[idx];
        int c = edge_index[E + e];
        const float* wp = buf + (size_t)e * 192;
        float w0 = wp[lane];
        float w1 = wp[64 + lane];
        float w2 = wp[128 + lane];
        const float* tp = Tn + (size_t)c * 640;
        a0 += w0 * tp[lane];
        a1 += w1 * tp[64 + lane];
        a2 += w1 * tp[128 + lane];
        a3 += w1 * tp[192 + lane];
        a4 += w2 * tp[256 + lane];
        a5 += w2 * tp[320 + lane];
        a6 += w2 * tp[384 + lane];
        a7 += w2 * tp[448 + lane];
        a8 += w2 * tp[512 + lane];
        a9 += w2 * tp[576 + lane];
    }
    float* mp = Mn + (size_t)n * 640;
    mp[lane] = a0;
    mp[64 + lane] = a1;  mp[128 + lane] = a2; mp[192 + lane] = a3;
    mp[256 + lane] = a4; mp[320 + lane] = a5; mp[384 + lane] = a6;
    mp[448 + lane] = a7; mp[512 + lane] = a8; mp[576 + lane] = a9;
}

// ---------------- node_post --------------------------------------------------
__global__ __launch_bounds__(64) void node_post(
    const float* __restrict__ X,
    const float* __restrict__ Tn, const float* __restrict__ Mn,
    const float* __restrict__ Wt3, const float* __restrict__ Wt4, const float* __restrict__ Wt5,
    float* __restrict__ out)
{
    int n = blockIdx.x, h = threadIdx.x;
    const float* Xb = X + (size_t)n * 9 * HD + h;
    float x[9];
    float nr = 0.f;
#pragma unroll
    for (int i = 0; i < 9; ++i) { x[i] = Xb[i * HD]; nr += x[i] * x[i]; }
    float xinv = 1.0f / (nr + 1.0f);
#pragma unroll
    for (int i = 0; i < 9; ++i) x[i] *= xinv;

    const float* tp = Tn + (size_t)n * 640 + h;
    const float* mp = Mn + (size_t)n * 640 + h;
    float yI = tp[0], mI = mp[0];
    float yA[3], yS[6], mA[3], mS[6];
#pragma unroll
    for (int j = 0; j < 3; ++j) { yA[j] = tp[(1 + j) * 64]; mA[j] = mp[(1 + j) * 64]; }
#pragma unroll
    for (int j = 0; j < 6; ++j) { yS[j] = tp[(4 + j) * 64]; mS[j] = mp[(4 + j) * 64]; }

    float M[3][3] = {
        { mI + mS[0],     mA[0] + mS[1],   mA[1] + mS[2] },
        { -mA[0] + mS[1], mI + mS[3],      mA[2] + mS[4] },
        { -mA[1] + mS[2], -mA[2] + mS[4],  mI + mS[5] } };
    float Y[3][3] = {
        { yI + yS[0],     yA[0] + yS[1],   yA[1] + yS[2] },
        { -yA[0] + yS[1], yI + yS[3],      yA[2] + yS[4] },
        { -yA[1] + yS[2], -yA[2] + yS[4],  yI + yS[5] } };

    float Cm[3][3];
    float nrm = 0.f;
#pragma unroll
    for (int a = 0; a < 3; ++a) {
#pragma unroll
        for (int b = 0; b < 3; ++b) {
            float s = 0.f;
#pragma unroll
            for (int c = 0; c < 3; ++c) s += M[a][c] * Y[c][b] + Y[a][c] * M[c][b];
            Cm[a][b] = s;
            nrm += s * s;
        }
    }
    float inv = 1.0f / (nrm + 1.0f);
    float tr3 = (Cm[0][0] + Cm[1][1] + Cm[2][2]) * (1.0f / 3.0f);

    __shared__ float comp[10][HD];
    comp[0][h] = tr3 * inv;
    comp[1][h] = 0.5f * (Cm[0][1] - Cm[1][0]) * inv;
    comp[2][h] = 0.5f * (Cm[0][2] - Cm[2][0]) * inv;
    comp[3][h] = 0.5f * (Cm[1][2] - Cm[2][1]) * inv;
    comp[4][h] = (Cm[0][0] - tr3) * inv;
    comp[5][h] = 0.5f * (Cm[0][1] + Cm[1][0]) * inv;
    comp[6][h] = 0.5f * (Cm[0][2] + Cm[2][0]) * inv;
    comp[7][h] = (Cm[1][1] - tr3) * inv;
    comp[8][h] = 0.5f * (Cm[1][2] + Cm[2][1]) * inv;
    comp[9][h] = (Cm[2][2] - tr3) * inv;
    __syncthreads();

    float acc[10];
#pragma unroll
    for (int i = 0; i < 10; ++i) acc[i] = 0.f;
    for (int k = 0; k < HD; ++k) {
        float w3 = Wt3[k * HD + h];
        float w4 = Wt4[k * HD + h];
        float w5 = Wt5[k * HD + h];
        acc[0] += comp[0][k] * w3;
        acc[1] += comp[1][k] * w4;
        acc[2] += comp[2][k] * w4;
        acc[3] += comp[3][k] * w4;
#pragma unroll
        for (int j = 0; j < 6; ++j) acc[4 + j] += comp[4 + j][k] * w5;
    }
    float D[3][3] = {
        { acc[0] + acc[4],  acc[1] + acc[5],  acc[2] + acc[6] },
        { -acc[1] + acc[5], acc[0] + acc[7],  acc[3] + acc[8] },
        { -acc[2] + acc[6], -acc[3] + acc[8], acc[0] + acc[9] } };

    float* ob = out + (size_t)n * 9 * HD + h;
#pragma unroll
    for (int a = 0; a < 3; ++a) {
#pragma unroll
        for (int b = 0; b < 3; ++b) {
            float s = 0.f;
#pragma unroll
            for (int c = 0; c < 3; ++c) s += D[a][c] * D[c][b];
            ob[(a * 3 + b) * HD] = x[a * 3 + b] + D[a][b] + s;
        }
    }
}

// ---------------- launch ------------------------------------------------------
extern "C" void kernel_launch(void* const* d_in, const int* in_sizes, int n_in,
                              void* d_out, int out_size, void* d_ws, size_t ws_size,
                              hipStream_t stream)
{
    const float* X           = (const float*)d_in[0];
    const float* charges     = (const float*)d_in[1];
    const float* edge_weight = (const float*)d_in[2];
    const float* edge_attr   = (const float*)d_in[3];
    const int*   edge_index  = (const int*)d_in[4];
    const float* Ws1 = (const float*)d_in[5];
    const float* bs1 = (const float*)d_in[6];
    const float* Ws2 = (const float*)d_in[7];
    const float* bs2 = (const float*)d_in[8];
    const float* Ws3 = (const float*)d_in[9];
    const float* bs3 = (const float*)d_in[10];
    const float* Wt0 = (const float*)d_in[11];
    const float* Wt1 = (const float*)d_in[12];
    const float* Wt2 = (const float*)d_in[13];
    const float* Wt3 = (const float*)d_in[14];
    const float* Wt4 = (const float*)d_in[15];
    const float* Wt5 = (const float*)d_in[16];

    int N = in_sizes[0] / (9 * HD);
    int E = in_sizes[2];

    float* ws = (float*)d_ws;
    float* Tn  = ws;                              // N*640
    float* Mn  = Tn + (size_t)N * 640;            // N*640
    float* buf = Mn + (size_t)N * 640;            // E*192 (h2 head -> w in place)
    float* cvA = buf + (size_t)E * 192;           // E
    int* cnt   = (int*)(cvA + E);                 // N
    int* offs  = cnt + N;                         // N+1
    int* curs  = offs + N + 1;                    // N
    int* order = curs + N;                        // E

    hipMemsetAsync(cnt, 0, (size_t)N * sizeof(int), stream);

    node_pre<<<N, 64, 0, stream>>>(X, Wt0, Wt1, Wt2, Tn);

    int nbE256 = (E + 255) / 256;
    count_kernel<<<nbE256, 256, 0, stream>>>(edge_index, cnt, E);
    scan_kernel<<<1, 1024, 0, stream>>>(cnt, offs, curs, N);
    place_kernel<<<nbE256, 256, 0, stream>>>(edge_index, curs, order, E);

    int nbE64 = (E + 63) / 64;
    mlp_l12<<<nbE64, 64, 0, stream>>>(edge_attr, charges, edge_weight, edge_index,
                                      Ws1, bs1, Ws2, bs2, buf, cvA, E);
    mlp_l3<<<nbE64, 64, 0, stream>>>(Ws3, bs3, cvA, buf, E);

    msg_kernel<<<N, 64, 0, stream>>>(buf, order, offs, edge_index, Tn, Mn, E);

    node_post<<<N, 64, 0, stream>>>(X, Tn, Mn, Wt3, Wt4, Wt5, (float*)d_out);
}